// Round 1
// baseline (544.123 us; speedup 1.0000x reference)
//
#include <hip/hip_runtime.h>
#include <hip/hip_bf16.h>
#include <math.h>

#define BDIM 1024   // d_in
#define NP   130    // 2L
#define LL   65     // L
#define NPAD 144    // padded N for gemm1
#define KP2  160    // padded K for gemm2
#define DOUT 512

typedef __attribute__((ext_vector_type(4))) float f32x4;
typedef __attribute__((ext_vector_type(8))) __bf16 bf16x8;

// ---------------------------------------------------------------------------
// K0a: Wbf[144][1024] bf16, rows >=130 zeroed (ws is 0xAA-poisoned each call)
// ---------------------------------------------------------------------------
__global__ void fill_wbf(const float* __restrict__ W, __bf16* __restrict__ Wbf) {
  int idx = blockIdx.x * 256 + threadIdx.x;   // 144*1024
  int c = idx >> 10, k = idx & 1023;
  float v = (c < NP) ? W[c * BDIM + k] : 0.f;
  Wbf[idx] = (__bf16)v;
}

// ---------------------------------------------------------------------------
// K0b: Mt[1024][160] bf16 — TRANSPOSED M' so gemm2 B-frags are k-contiguous.
// Mt[col][k]: col=2d+im; k<65: j=k, (Re:cos, Im:sin); k>=65: j=k-65,
// (Re:-sin, Im:cos). k in [130,160) zero.
// v2: one thread per (d, jj); jj<65 computes ONE f64 sincos and writes the 4
// symmetric entries (cos/sin appear at k=j and k=65+j for both im cols);
// jj in [65,80) writes the 2x2 zero-pad entries. 5x less f64 trig than v1.
// ---------------------------------------------------------------------------
__global__ void fill_mt(__bf16* __restrict__ Mt) {
  int idx = blockIdx.x * 256 + threadIdx.x;   // 512*80 = 40960 exactly
  int d = idx / 80, jj = idx - d * 80;
  __bf16* col0 = Mt + (size_t)(2 * d) * KP2;      // im=0 (Re path)
  __bf16* col1 = Mt + (size_t)(2 * d + 1) * KP2;  // im=1 (Im path)
  if (jj < LL) {
    double theta = M_PI * (-1.0 + (2.0 * (double)d + 1.0) / 512.0);
    double ph = (double)jj * theta;
    double s = sin(ph), c = cos(ph);
    col0[jj]      = (__bf16)(float)c;      // k<65,  im=0: cos
    col1[jj]      = (__bf16)(float)s;      // k<65,  im=1: sin
    col0[LL + jj] = (__bf16)(float)(-s);   // k>=65, im=0: -sin
    col1[LL + jj] = (__bf16)(float)c;      // k>=65, im=1: cos
  } else {
    int k = NP + (jj - LL);                // 130..144
    col0[k] = (__bf16)0.f; col1[k] = (__bf16)0.f;
    k += 15;                               // 145..159
    col0[k] = (__bf16)0.f; col1[k] = (__bf16)0.f;
  }
}

// ---------------------------------------------------------------------------
// K1: MFMA GEMM1  P[row][c] = bf16( X[row]@W[c] + b[c] ),
//     R0[row] = 1/(512*sum_c p^2).  No LDS: A-frags direct from global fp32
//     (cvt in-reg), B-frags direct bf16 from Wbf (L2-hot).
// v2: 16 rows/wave (was 32) -> 4096 waves total = 4 blocks/CU, 4 waves/SIMD
//     (acc = 9 f32x4 = 36 VGPR), plus explicit next-k A-register prefetch so
//     HBM loads for k+32 are in flight across the cvt+MFMA of k.
// Block = 4 waves x 16 rows = 64 rows. Grid = B/64 = 1024 blocks.
// ---------------------------------------------------------------------------
__global__ __launch_bounds__(256) void gemm1(
    const float* __restrict__ X, const __bf16* __restrict__ Wbf,
    const float* __restrict__ bias, __bf16* __restrict__ P,
    float* __restrict__ R0) {
  const int tid  = threadIdx.x;
  const int w    = tid >> 6;
  const int lane = tid & 63;
  const int l15  = lane & 15;
  const int quad = lane >> 4;
  const long rowbase = (long)blockIdx.x * 64 + w * 16;

  f32x4 acc[9];
#pragma unroll
  for (int j = 0; j < 9; j++) acc[j] = (f32x4){0.f, 0.f, 0.f, 0.f};

  const float*  xptr = X   + (rowbase + l15) * BDIM + quad * 8;
  const __bf16* wptr = Wbf + (long)l15 * BDIM + quad * 8;

  // software pipeline: x0/x1 hold the current k-step's A bytes
  f32x4 x0 = *(const f32x4*)(xptr);
  f32x4 x1 = *(const f32x4*)(xptr + 4);

#pragma unroll 2
  for (int k0 = 0; k0 < BDIM; k0 += 32) {
    // issue next-step A loads FIRST so they overlap cvt+MFMA below
    const int kn = (k0 + 32 < BDIM) ? (k0 + 32) : k0;  // clamped (L1-hot) tail
    f32x4 n0 = *(const f32x4*)(xptr + kn);
    f32x4 n1 = *(const f32x4*)(xptr + kn + 4);

    bf16x8 a;
    a[0] = (__bf16)x0[0]; a[1] = (__bf16)x0[1];
    a[2] = (__bf16)x0[2]; a[3] = (__bf16)x0[3];
    a[4] = (__bf16)x1[0]; a[5] = (__bf16)x1[1];
    a[6] = (__bf16)x1[2]; a[7] = (__bf16)x1[3];

#pragma unroll
    for (int j = 0; j < 9; j++) {
      bf16x8 b = *(const bf16x8*)(wptr + (long)j * 16 * BDIM + k0);
      acc[j] = __builtin_amdgcn_mfma_f32_16x16x32_bf16(a, b, acc[j], 0, 0, 0);
    }
    x0 = n0; x1 = n1;
  }

  // epilogue: bias, P store (bf16, zero-padded), r0 reduction
  float s[4] = {0.f, 0.f, 0.f, 0.f};

#pragma unroll
  for (int j = 0; j < 9; j++) {
    int c = j * 16 + l15;
    float bj = (c < NP) ? bias[c] : 0.f;
#pragma unroll
    for (int reg = 0; reg < 4; reg++) {
      long row = rowbase + quad * 4 + reg;
      float pv = acc[j][reg] + bj;
      if (c >= NP) pv = 0.f;                 // zero the 130..143 pad
      P[row * KP2 + c] = (__bf16)pv;
      s[reg] = fmaf(pv, pv, s[reg]);
    }
  }
  // zero pad cols 144..159
#pragma unroll
  for (int reg = 0; reg < 4; reg++) {
    long row = rowbase + quad * 4 + reg;
    P[row * KP2 + NPAD + l15] = (__bf16)0.f;
  }
  // reduce sum p^2 across the 16-lane col groups; store reciprocal factor
#pragma unroll
  for (int reg = 0; reg < 4; reg++) {
    float v = s[reg];
    v += __shfl_xor(v, 1);
    v += __shfl_xor(v, 2);
    v += __shfl_xor(v, 4);
    v += __shfl_xor(v, 8);
    if (l15 == 0) {
      long row = rowbase + quad * 4 + reg;
      R0[row] = 1.0f / (512.0f * v);
    }
  }
}

// ---------------------------------------------------------------------------
// K2: MFMA GEMM2  A[row][acol] = P[row][0:160] @ Mt[acol][0:160]^T, fused
//     out[row][d] = __logf(|A|^2 * R0[row] + 1e-5), d = acol>>1.
// Block = 128 rows x 128 acols, 2x2 waves of 64x64. K=160 (5 steps).
// Grid x = row-blocks (fastest) so the Mt tile stays L2-hot per y.
// v2: R0 gathers hoisted out of the tile loops (32 -> 8 loads/lane).
// ---------------------------------------------------------------------------
__global__ __launch_bounds__(256) void gemm2(
    const __bf16* __restrict__ P, const __bf16* __restrict__ Mt,
    const float* __restrict__ R0, float* __restrict__ out) {
  const int tid  = threadIdx.x;
  const int w    = tid >> 6;
  const int wr   = w >> 1, wc = w & 1;
  const int lane = tid & 63;
  const int l15  = lane & 15;
  const int quad = lane >> 4;
  const long rowbase = (long)blockIdx.x * 128 + wr * 64;
  const int  colbase = blockIdx.y * 128 + wc * 64;

  f32x4 acc[4][4];   // [rtile][ctile]
#pragma unroll
  for (int rt = 0; rt < 4; rt++)
#pragma unroll
    for (int ct = 0; ct < 4; ct++) acc[rt][ct] = (f32x4){0.f, 0.f, 0.f, 0.f};

  const __bf16* pptr = P  + (rowbase + l15) * KP2 + quad * 8;
  const __bf16* mptr = Mt + (long)(colbase + l15) * KP2 + quad * 8;

#pragma unroll
  for (int k0 = 0; k0 < KP2; k0 += 32) {
    bf16x8 a[4], b[4];
#pragma unroll
    for (int t = 0; t < 4; t++) a[t] = *(const bf16x8*)(pptr + (long)t * 16 * KP2 + k0);
#pragma unroll
    for (int t = 0; t < 4; t++) b[t] = *(const bf16x8*)(mptr + (long)t * 16 * KP2 + k0);
#pragma unroll
    for (int rt = 0; rt < 4; rt++)
#pragma unroll
      for (int ct = 0; ct < 4; ct++)
        acc[rt][ct] = __builtin_amdgcn_mfma_f32_16x16x32_bf16(a[rt], b[ct], acc[rt][ct], 0, 0, 0);
  }

  // hoist the R0 gathers: row depends only on (rt, q) for this lane
  const int par = lane & 1;
  float inv[4][2];
#pragma unroll
  for (int rt = 0; rt < 4; rt++)
#pragma unroll
    for (int q = 0; q < 2; q++)
      inv[rt][q] = R0[rowbase + rt * 16 + quad * 4 + par * 2 + q];

  // epilogue: |A|^2 via lane-pair shfl, parity-split log + store
#pragma unroll
  for (int rt = 0; rt < 4; rt++) {
#pragma unroll
    for (int ct = 0; ct < 4; ct++) {
      const int d = (colbase >> 1) + ct * 8 + (l15 >> 1);
      float t[4];
#pragma unroll
      for (int reg = 0; reg < 4; reg++) {
        float v = acc[rt][ct][reg];
        t[reg] = v * v;
        t[reg] += __shfl_xor(t[reg], 1);    // Re^2 + Im^2, both lanes of pair
      }
#pragma unroll
      for (int q = 0; q < 2; q++) {
        int reg = par * 2 + q;              // even lane: regs 0,1; odd: 2,3
        long row = rowbase + rt * 16 + quad * 4 + reg;
        out[row * DOUT + d] = __logf(fmaf(t[reg], inv[rt][q], 1e-5f));
      }
    }
  }
}

// ---------------------------------------------------------------------------
extern "C" void kernel_launch(void* const* d_in, const int* in_sizes, int n_in,
                              void* d_out, int out_size, void* d_ws, size_t ws_size,
                              hipStream_t stream) {
  const float* X    = (const float*)d_in[0];   // [B x 1024]
  const float* W    = (const float*)d_in[1];   // [130 x 1024]
  const float* bias = (const float*)d_in[2];   // [130]
  float* out = (float*)d_out;                  // [B x 512]
  const int B = in_sizes[0] / BDIM;            // 65536

  // ws layout: P[B*160] bf16 | Wbf[144*1024] bf16 | Mt[1024*160] bf16 | R0[B] f32
  char* ws = (char*)d_ws;
  __bf16* P   = (__bf16*)ws;                         ws += (size_t)B * KP2 * 2;
  __bf16* Wbf = (__bf16*)ws;                         ws += (size_t)NPAD * BDIM * 2;
  __bf16* Mt  = (__bf16*)ws;                         ws += (size_t)BDIM * KP2 * 2;
  float*  R0  = (float*)ws;

  fill_wbf<<<(NPAD * BDIM) / 256, 256, 0, stream>>>(W, Wbf);
  fill_mt<<<(512 * 80) / 256, 256, 0, stream>>>(Mt);
  gemm1<<<B / 64, 256, 0, stream>>>(X, Wbf, bias, P, R0);
  gemm2<<<dim3(B / 128, 8), 256, 0, stream>>>(P, Mt, R0, out);
}

// Round 2
// 490.971 us; speedup vs baseline: 1.1083x; 1.1083x over previous
//
#include <hip/hip_runtime.h>
#include <hip/hip_bf16.h>
#include <math.h>

#define BDIM 1024   // d_in
#define NP   130    // 2L
#define LL   65     // L
#define NPAD 144    // padded N for gemm1
#define KP2  160    // padded K for gemm2
#define DOUT 512
#define BK   32     // k-step for gemm1

typedef __attribute__((ext_vector_type(4))) float f32x4;
typedef __attribute__((ext_vector_type(8))) __bf16 bf16x8;

__device__ __forceinline__ void gload_lds16(const void* g, void* l) {
  __builtin_amdgcn_global_load_lds(
      (const __attribute__((address_space(1))) void*)g,
      (__attribute__((address_space(3))) void*)l, 16, 0, 0);
}

// ---------------------------------------------------------------------------
// K0a: Wbf[144][1024] bf16, rows >=130 zeroed (ws is 0xAA-poisoned each call)
// ---------------------------------------------------------------------------
__global__ void fill_wbf(const float* __restrict__ W, __bf16* __restrict__ Wbf) {
  int idx = blockIdx.x * 256 + threadIdx.x;   // 144*1024
  int c = idx >> 10, k = idx & 1023;
  float v = (c < NP) ? W[c * BDIM + k] : 0.f;
  Wbf[idx] = (__bf16)v;
}

// ---------------------------------------------------------------------------
// K0b: Mt[1024][160] bf16 — TRANSPOSED M' so gemm2 B-frags are k-contiguous.
// One thread per (d, jj); jj<65 computes ONE f64 sincos, writes 4 entries.
// ---------------------------------------------------------------------------
__global__ void fill_mt(__bf16* __restrict__ Mt) {
  int idx = blockIdx.x * 256 + threadIdx.x;   // 512*80 = 40960 exactly
  int d = idx / 80, jj = idx - d * 80;
  __bf16* col0 = Mt + (size_t)(2 * d) * KP2;      // im=0 (Re path)
  __bf16* col1 = Mt + (size_t)(2 * d + 1) * KP2;  // im=1 (Im path)
  if (jj < LL) {
    double theta = M_PI * (-1.0 + (2.0 * (double)d + 1.0) / 512.0);
    double ph = (double)jj * theta;
    double s = sin(ph), c = cos(ph);
    col0[jj]      = (__bf16)(float)c;      // k<65,  im=0: cos
    col1[jj]      = (__bf16)(float)s;      // k<65,  im=1: sin
    col0[LL + jj] = (__bf16)(float)(-s);   // k>=65, im=0: -sin
    col1[LL + jj] = (__bf16)(float)c;      // k>=65, im=1: cos
  } else {
    int k = NP + (jj - LL);                // 130..144
    col0[k] = (__bf16)0.f; col1[k] = (__bf16)0.f;
    k += 15;                               // 145..159
    col0[k] = (__bf16)0.f; col1[k] = (__bf16)0.f;
  }
}

// ---------------------------------------------------------------------------
// K1 v3: m97-style global_load_lds double-buffered pipeline.
//   A tile: 64 rows x 32 f32 (8 KB)  = 512 16B-chunks, 2 block-wide DMA calls.
//     LDS layout [row][chunk 0..7], source pre-swizzled cg = cs ^ (row&7)
//     -> read-side ds_read_b128 is 2-way (free) instead of 16-way.
//   B tile: 144 rows x 32 bf16 (9216 B) = 576 chunks, 2 calls + 1 wave-call.
//     LDS layout [row][chunk 0..3], source pre-swizzled cg = cs ^ ((row>>1)&3)
//     -> read-side 2-way (free) instead of 8-way.
//   One __syncthreads per k-step (full vmcnt drain = the DMA fence).
// Block = 4 waves x 16 rows = 64 rows; grid = B/64 = 1024 = 4 blocks/CU.
// ---------------------------------------------------------------------------
__global__ __launch_bounds__(256, 4) void gemm1(
    const float* __restrict__ X, const __bf16* __restrict__ Wbf,
    const float* __restrict__ bias, __bf16* __restrict__ P,
    float* __restrict__ R0) {
  const int tid  = threadIdx.x;
  const int w    = tid >> 6;
  const int lane = tid & 63;
  const int l15  = lane & 15;
  const int quad = lane >> 4;
  const long row0   = (long)blockIdx.x * 64;      // block's first row
  const long rowbase = row0 + w * 16;             // wave's first row

  __shared__ __align__(16) char Asmem[2][64 * BK * 4];    // fp32
  __shared__ __align__(16) char Bsmem[2][NPAD * BK * 2];  // bf16

  // ---- staging helpers (block-wide) ----
  auto stageA = [&](int buf, int k0) {
#pragma unroll
    for (int c = 0; c < 2; c++) {
      int t   = c * 256 + tid;        // chunk slot 0..511
      int row = t >> 3, cs = t & 7;
      int cg  = cs ^ (row & 7);       // pre-swizzled global chunk
      const char* g = (const char*)(X + (row0 + row) * BDIM + k0) + cg * 16;
      gload_lds16(g, &Asmem[buf][t * 16]);
    }
  };
  auto stageB = [&](int buf, int k0) {
#pragma unroll
    for (int c = 0; c < 2; c++) {
      int t   = c * 256 + tid;        // chunk slot 0..511
      int row = t >> 2, cs = t & 3;
      int cg  = cs ^ ((row >> 1) & 3);
      const char* g = (const char*)(Wbf + (long)row * BDIM + k0) + cg * 16;
      gload_lds16(g, &Bsmem[buf][t * 16]);
    }
    if (tid < 64) {                    // slots 512..575 (rows 128..143)
      int t   = 512 + tid;
      int row = t >> 2, cs = t & 3;
      int cg  = cs ^ ((row >> 1) & 3);
      const char* g = (const char*)(Wbf + (long)row * BDIM + k0) + cg * 16;
      gload_lds16(g, &Bsmem[buf][t * 16]);
    }
  };

  f32x4 acc[9];
#pragma unroll
  for (int j = 0; j < 9; j++) acc[j] = (f32x4){0.f, 0.f, 0.f, 0.f};

  stageA(0, 0);
  stageB(0, 0);
  __syncthreads();    // compiler emits vmcnt(0) drain before s_barrier

  const int r  = w * 16 + l15;         // local A row
  const int s0 = (2 * quad) ^ (r & 7); // swizzled A chunk slots
  const int s1 = s0 ^ 1;

#pragma unroll 2
  for (int k0 = 0; k0 < BDIM; k0 += BK) {
    const int cur = (k0 >> 5) & 1;
    if (k0 + BK < BDIM) { stageA(cur ^ 1, k0 + BK); stageB(cur ^ 1, k0 + BK); }

    // A frags from LDS (fp32 -> bf16 in-reg)
    const char* ab = &Asmem[cur][0];
    f32x4 x0 = *(const f32x4*)(ab + r * 128 + s0 * 16);  // floats q*8..+3
    f32x4 x1 = *(const f32x4*)(ab + r * 128 + s1 * 16);  // floats q*8+4..+7
    bf16x8 a;
    a[0] = (__bf16)x0[0]; a[1] = (__bf16)x0[1];
    a[2] = (__bf16)x0[2]; a[3] = (__bf16)x0[3];
    a[4] = (__bf16)x1[0]; a[5] = (__bf16)x1[1];
    a[6] = (__bf16)x1[2]; a[7] = (__bf16)x1[3];

    const char* bb = &Bsmem[cur][0];
#pragma unroll
    for (int j = 0; j < 9; j++) {
      int jr = j * 16 + l15;
      int s  = quad ^ ((jr >> 1) & 3);
      bf16x8 b = *(const bf16x8*)(bb + jr * 64 + s * 16);
      acc[j] = __builtin_amdgcn_mfma_f32_16x16x32_bf16(a, b, acc[j], 0, 0, 0);
    }
    __syncthreads();   // drains this iter's DMA for next iter's reads
  }

  // epilogue: bias, P store (bf16, zero-padded), r0 reduction
  float s[4] = {0.f, 0.f, 0.f, 0.f};

#pragma unroll
  for (int j = 0; j < 9; j++) {
    int c = j * 16 + l15;
    float bj = (c < NP) ? bias[c] : 0.f;
#pragma unroll
    for (int reg = 0; reg < 4; reg++) {
      long row = rowbase + quad * 4 + reg;
      float pv = acc[j][reg] + bj;
      if (c >= NP) pv = 0.f;                 // zero the 130..143 pad
      P[row * KP2 + c] = (__bf16)pv;
      s[reg] = fmaf(pv, pv, s[reg]);
    }
  }
  // zero pad cols 144..159
#pragma unroll
  for (int reg = 0; reg < 4; reg++) {
    long row = rowbase + quad * 4 + reg;
    P[row * KP2 + NPAD + l15] = (__bf16)0.f;
  }
  // reduce sum p^2 across the 16-lane col groups; store reciprocal factor
#pragma unroll
  for (int reg = 0; reg < 4; reg++) {
    float v = s[reg];
    v += __shfl_xor(v, 1);
    v += __shfl_xor(v, 2);
    v += __shfl_xor(v, 4);
    v += __shfl_xor(v, 8);
    if (l15 == 0) {
      long row = rowbase + quad * 4 + reg;
      R0[row] = 1.0f / (512.0f * v);
    }
  }
}

// ---------------------------------------------------------------------------
// K2: MFMA GEMM2  A[row][acol] = P[row][0:160] @ Mt[acol][0:160]^T, fused
//     out[row][d] = __logf(|A|^2 * R0[row] + 1e-5), d = acol>>1.
// (unchanged this round for clean attribution)
// ---------------------------------------------------------------------------
__global__ __launch_bounds__(256) void gemm2(
    const __bf16* __restrict__ P, const __bf16* __restrict__ Mt,
    const float* __restrict__ R0, float* __restrict__ out) {
  const int tid  = threadIdx.x;
  const int w    = tid >> 6;
  const int wr   = w >> 1, wc = w & 1;
  const int lane = tid & 63;
  const int l15  = lane & 15;
  const int quad = lane >> 4;
  const long rowbase = (long)blockIdx.x * 128 + wr * 64;
  const int  colbase = blockIdx.y * 128 + wc * 64;

  f32x4 acc[4][4];   // [rtile][ctile]
#pragma unroll
  for (int rt = 0; rt < 4; rt++)
#pragma unroll
    for (int ct = 0; ct < 4; ct++) acc[rt][ct] = (f32x4){0.f, 0.f, 0.f, 0.f};

  const __bf16* pptr = P  + (rowbase + l15) * KP2 + quad * 8;
  const __bf16* mptr = Mt + (long)(colbase + l15) * KP2 + quad * 8;

#pragma unroll
  for (int k0 = 0; k0 < KP2; k0 += 32) {
    bf16x8 a[4], b[4];
#pragma unroll
    for (int t = 0; t < 4; t++) a[t] = *(const bf16x8*)(pptr + (long)t * 16 * KP2 + k0);
#pragma unroll
    for (int t = 0; t < 4; t++) b[t] = *(const bf16x8*)(mptr + (long)t * 16 * KP2 + k0);
#pragma unroll
    for (int rt = 0; rt < 4; rt++)
#pragma unroll
      for (int ct = 0; ct < 4; ct++)
        acc[rt][ct] = __builtin_amdgcn_mfma_f32_16x16x32_bf16(a[rt], b[ct], acc[rt][ct], 0, 0, 0);
  }

  // hoist the R0 gathers: row depends only on (rt, q) for this lane
  const int par = lane & 1;
  float inv[4][2];
#pragma unroll
  for (int rt = 0; rt < 4; rt++)
#pragma unroll
    for (int q = 0; q < 2; q++)
      inv[rt][q] = R0[rowbase + rt * 16 + quad * 4 + par * 2 + q];

  // epilogue: |A|^2 via lane-pair shfl, parity-split log + store
#pragma unroll
  for (int rt = 0; rt < 4; rt++) {
#pragma unroll
    for (int ct = 0; ct < 4; ct++) {
      const int d = (colbase >> 1) + ct * 8 + (l15 >> 1);
      float t[4];
#pragma unroll
      for (int reg = 0; reg < 4; reg++) {
        float v = acc[rt][ct][reg];
        t[reg] = v * v;
        t[reg] += __shfl_xor(t[reg], 1);    // Re^2 + Im^2, both lanes of pair
      }
#pragma unroll
      for (int q = 0; q < 2; q++) {
        int reg = par * 2 + q;              // even lane: regs 0,1; odd: 2,3
        long row = rowbase + rt * 16 + quad * 4 + reg;
        out[row * DOUT + d] = __logf(fmaf(t[reg], inv[rt][q], 1e-5f));
      }
    }
  }
}

// ---------------------------------------------------------------------------
extern "C" void kernel_launch(void* const* d_in, const int* in_sizes, int n_in,
                              void* d_out, int out_size, void* d_ws, size_t ws_size,
                              hipStream_t stream) {
  const float* X    = (const float*)d_in[0];   // [B x 1024]
  const float* W    = (const float*)d_in[1];   // [130 x 1024]
  const float* bias = (const float*)d_in[2];   // [130]
  float* out = (float*)d_out;                  // [B x 512]
  const int B = in_sizes[0] / BDIM;            // 65536

  // ws layout: P[B*160] bf16 | Wbf[144*1024] bf16 | Mt[1024*160] bf16 | R0[B] f32
  char* ws = (char*)d_ws;
  __bf16* P   = (__bf16*)ws;                         ws += (size_t)B * KP2 * 2;
  __bf16* Wbf = (__bf16*)ws;                         ws += (size_t)NPAD * BDIM * 2;
  __bf16* Mt  = (__bf16*)ws;                         ws += (size_t)BDIM * KP2 * 2;
  float*  R0  = (float*)ws;

  fill_wbf<<<(NPAD * BDIM) / 256, 256, 0, stream>>>(W, Wbf);
  fill_mt<<<(512 * 80) / 256, 256, 0, stream>>>(Mt);
  gemm1<<<B / 64, 256, 0, stream>>>(X, Wbf, bias, P, R0);
  gemm2<<<dim3(B / 128, 8), 256, 0, stream>>>(P, Mt, R0, out);
}